// Round 1
// 766.068 us; speedup vs baseline: 1.2457x; 1.2457x over previous
//
#include <hip/hip_runtime.h>
#include <cstdint>
#include <cstddef>

constexpr int kBS = 8;
constexpr int kNC = 64;
constexpr int kC = 256;
constexpr int kD = 32;
constexpr int kK = 16;
constexpr int kKB = 8;
constexpr int kALPHA = 4;
constexpr int kB = 16;
constexpr int kHS = 64;
constexpr int kHM = 64;
constexpr int kHMOD = 32;
constexpr int kN = kNC * kC;               // 16384
constexpr int kMODIN = kK + 3 * kD + 1;    // 113
constexpr int kMODOUT = kK + kKB + 1 + kD; // 57
constexpr int kXS = 116;                   // mod-x LDS row stride (464B, 16B mult)
constexpr int kW1S = 100;                  // state w1 LDS row stride (400B, 16B mult)
constexpr int kSLAB = 36;                  // slab row stride (144B, 16B mult)

constexpr size_t kO1 = (size_t)kBS * kNC * kD;        // readout
constexpr size_t kO2 = kO1 + (size_t)kBS * kN * kD;   // + h_new
constexpr size_t kO3 = kO2 + (size_t)kBS * kN * kD;   // + msg

__device__ __forceinline__ float sigmoidf_(float x) {
    return 1.0f / (1.0f + __expf(-x));
}
__device__ __forceinline__ float rdlane(float v, int l) {
    return __int_as_float(__builtin_amdgcn_readlane(__float_as_int(v), l));
}

// ---------------- Kernel A: per-neuron modulation MLP --------------------
// 256 threads = 4 waves, one neuron per wave. x in LDS (broadcast reads),
// W1 rows read per-lane from global (hh = lane&31, so lanes l and l+32 share
// a row), layer-2 hidden values pulled cross-lane via v_readlane -> no LDS
// for hid/W2 at all.
// modout row layout (mos=60): [0..15]=wcon [16..23]=wb [24]=decay [28..59]=prim
// fallback (mos=57): original tight layout, prim at 25.
__global__ __launch_bounds__(256) void mod_mlp_kernel(
    const float* __restrict__ heb, const float* __restrict__ h,
    const float* __restrict__ dlog, const float* __restrict__ prim,
    const float* __restrict__ nid,
    const float* __restrict__ mw1, const float* __restrict__ mb1,
    const float* __restrict__ mw2, const float* __restrict__ mb2,
    float* __restrict__ modout, int mos, int poff)
{
    const int wv = threadIdx.x >> 6;
    const int lane = threadIdx.x & 63;
    const int n = (blockIdx.x << 2) | wv;

    __shared__ __align__(16) float xs[4][kBS * kXS];   // 4 x 928 f = 14848 B
    float* xw = xs[wv];

    // stage mod-input vectors for all 8 batches (this wave's neuron)
    for (int t = lane; t < kBS * kMODIN; t += 64) {
        int b = t / kMODIN;
        int i = t - b * kMODIN;
        size_t nb = (size_t)b * kN + n;
        float v;
        if (i < kK)                 v = heb[nb * kK + i];
        else if (i < kK + kD)       v = h[nb * kD + (i - kK)];
        else if (i == kK + kD)      v = dlog[nb];
        else if (i < kK + 2*kD + 1) v = prim[nb * kD + (i - (kK + kD + 1))];
        else                        v = nid[(size_t)n * kD + (i - (kK + 2*kD + 1))];
        xw[b * kXS + i] = v;
    }
    __syncthreads();

    // layer 1: lane computes hid[b][hh] for hh=lane&31 and 4 batches
    const int hh = lane & 31;
    const int bh = lane >> 5;                      // b parity
    const float* wg = mw1 + ((size_t)n * kHMOD + hh) * kMODIN;
    float a0 = 0.f, a1 = 0.f, a2 = 0.f, a3 = 0.f;
    #pragma unroll 4
    for (int q = 0; q < 28; ++q) {
        float w0 = wg[4*q+0], w1 = wg[4*q+1], w2 = wg[4*q+2], w3 = wg[4*q+3];
        const float4 x0 = *(const float4*)(xw + (bh+0) * kXS + 4*q);
        const float4 x1 = *(const float4*)(xw + (bh+2) * kXS + 4*q);
        const float4 x2 = *(const float4*)(xw + (bh+4) * kXS + 4*q);
        const float4 x3 = *(const float4*)(xw + (bh+6) * kXS + 4*q);
        a0 += w0*x0.x + w1*x0.y + w2*x0.z + w3*x0.w;
        a1 += w0*x1.x + w1*x1.y + w2*x1.z + w3*x1.w;
        a2 += w0*x2.x + w1*x2.y + w2*x2.z + w3*x2.w;
        a3 += w0*x3.x + w1*x3.y + w2*x3.z + w3*x3.w;
    }
    {
        float w112 = wg[112];
        a0 += w112 * xw[(bh+0)*kXS + 112];
        a1 += w112 * xw[(bh+2)*kXS + 112];
        a2 += w112 * xw[(bh+4)*kXS + 112];
        a3 += w112 * xw[(bh+6)*kXS + 112];
    }
    const float bb = mb1[(size_t)n * kHMOD + hh];
    float h0 = tanhf(a0 + bb);   // b = bh+0
    float h1 = tanhf(a1 + bb);   // b = bh+2
    float h2 = tanhf(a2 + bb);   // b = bh+4
    float h3 = tanhf(a3 + bb);   // b = bh+6

    // layer 2: lane = output o; hid[b][hh] via readlane
    const int o = (lane < kMODOUT) ? lane : (kMODOUT - 1);
    const float* w2g = mw2 + (size_t)n * (kHMOD * kMODOUT);
    float ob0=0.f, ob1=0.f, ob2=0.f, ob3=0.f, ob4=0.f, ob5=0.f, ob6=0.f, ob7=0.f;
    #pragma unroll
    for (int hx = 0; hx < kHMOD; ++hx) {
        float w = w2g[hx * kMODOUT + o];
        ob0 += rdlane(h0, hx)      * w;   // b=0 lives in lanes 0..31 (bh=0)
        ob1 += rdlane(h0, hx + 32) * w;   // b=1 lives in lanes 32..63
        ob2 += rdlane(h1, hx)      * w;
        ob3 += rdlane(h1, hx + 32) * w;
        ob4 += rdlane(h2, hx)      * w;
        ob5 += rdlane(h2, hx + 32) * w;
        ob6 += rdlane(h3, hx)      * w;
        ob7 += rdlane(h3, hx + 32) * w;
    }
    if (lane < kMODOUT) {
        const float bo = mb2[(size_t)n * kMODOUT + o];
        const int oo = (o < 25) ? o : (o + (poff - 25));
        modout[((size_t)0 * kN + n) * mos + oo] = ob0 + bo;
        modout[((size_t)1 * kN + n) * mos + oo] = ob1 + bo;
        modout[((size_t)2 * kN + n) * mos + oo] = ob2 + bo;
        modout[((size_t)3 * kN + n) * mos + oo] = ob3 + bo;
        modout[((size_t)4 * kN + n) * mos + oo] = ob4 + bo;
        modout[((size_t)5 * kN + n) * mos + oo] = ob5 + bo;
        modout[((size_t)6 * kN + n) * mos + oo] = ob6 + bo;
        modout[((size_t)7 * kN + n) * mos + oo] = ob7 + bo;
    }
}

// ---------------- Kernel B: per-cell message passing + state/msg MLPs -----
// One block per (b,nc); one thread per neuron c. All MLP weights staged in
// LDS once per block (w2 transposed), read as same-address ds_read_b128
// broadcasts -> removes the scalar-cache weight-stream stalls.
__global__ __launch_bounds__(256) void cell_kernel(
    const float* __restrict__ cc, const float* __restrict__ hin,
    const float* __restrict__ pmsg, const float* __restrict__ prim,
    const float* __restrict__ hebin, const float* __restrict__ nid,
    const float* __restrict__ sw1, const float* __restrict__ sb1,
    const float* __restrict__ sw2, const float* __restrict__ sb2,
    const float* __restrict__ mw1g, const float* __restrict__ mb1g,
    const float* __restrict__ mw2g, const float* __restrict__ mb2g,
    const int* __restrict__ conn, const int* __restrict__ bconn,
    const float* __restrict__ modout, float* __restrict__ out,
    int mos, int poff)
{
    const int nc = blockIdx.x;
    const int b  = blockIdx.y;
    const int c  = threadIdx.x;

    __shared__ __align__(16) float slab[kC * kSLAB];   // 36864 B
    __shared__ __align__(16) float w1s[kHS * kW1S];    // 25600 B  (state W1, rows of 97 pad 100)
    __shared__ __align__(16) float w2ts[kHS * kD];     //  8192 B  (state W2 transposed [hh][o])
    __shared__ __align__(16) float mw1s[kHM * 96];     // 24576 B  (msg W1, natural rows)
    __shared__ __align__(16) float mw2ts[kHM * kD];    //  8192 B  (msg W2 transposed)
    __shared__ float sb1s[kHS], sb2s[kD], mb1s[kHM], mb2s[kD];
    // total ~104 KB of 160 KB -> 1 block/CU

    const size_t cellrow = ((size_t)b * kNC + nc) * kC;
    const size_t nbase   = cellrow + c;

    // ---- stage weights ----
    for (int idx = c; idx < kHS * 97; idx += kC) {
        int r = idx / 97, ci = idx - r * 97;
        w1s[r * kW1S + ci] = sw1[idx];
    }
    for (int idx = c; idx < kHM * 96; idx += kC) mw1s[idx] = mw1g[idx];
    for (int idx = c; idx < kHS * kD; idx += kC) {      // sw2 is [o=32][hh=64]
        int o2 = idx >> 6, h2 = idx & 63;
        w2ts[h2 * kD + o2] = sw2[idx];
    }
    for (int idx = c; idx < kHM * kD; idx += kC) {
        int o2 = idx >> 6, h2 = idx & 63;
        mw2ts[h2 * kD + o2] = mw2g[idx];
    }
    if (c < kHS) sb1s[c] = sb1[c];
    if (c < kD)  sb2s[c] = sb2[c];
    if (c < kHM) mb1s[c] = mb1g[c];
    if (c < kD)  mb2s[c] = mb2g[c];

    // ---- stage this cell's prev_messages (coalesced, float4) ----
    {
        const float4* s4 = (const float4*)(pmsg + cellrow * kD);
        for (int i = c; i < (kC * kD) / 4; i += kC) {
            float4 v = s4[i];
            *(float4*)&slab[(i >> 3) * kSLAB + ((i & 7) << 2)] = v;
        }
    }

    // ---- per-thread loads (overlap with staging) ----
    float hreg[32];
    {
        const float4* src = (const float4*)(hin + nbase * kD);
        #pragma unroll
        for (int q = 0; q < 8; ++q) {
            float4 v = src[q];
            hreg[4*q] = v.x; hreg[4*q+1] = v.y; hreg[4*q+2] = v.z; hreg[4*q+3] = v.w;
        }
    }
    const float* mo = modout + nbase * mos;
    float wcon[16];
    if (poff == 28) {
        const float4* m4 = (const float4*)mo;
        float4 va = m4[0], vb = m4[1], vc = m4[2], vd = m4[3];
        wcon[0]=sigmoidf_(va.x);  wcon[1]=sigmoidf_(va.y);  wcon[2]=sigmoidf_(va.z);  wcon[3]=sigmoidf_(va.w);
        wcon[4]=sigmoidf_(vb.x);  wcon[5]=sigmoidf_(vb.y);  wcon[6]=sigmoidf_(vb.z);  wcon[7]=sigmoidf_(vb.w);
        wcon[8]=sigmoidf_(vc.x);  wcon[9]=sigmoidf_(vc.y);  wcon[10]=sigmoidf_(vc.z); wcon[11]=sigmoidf_(vc.w);
        wcon[12]=sigmoidf_(vd.x); wcon[13]=sigmoidf_(vd.y); wcon[14]=sigmoidf_(vd.z); wcon[15]=sigmoidf_(vd.w);
    } else {
        #pragma unroll
        for (int k = 0; k < 16; ++k) wcon[k] = sigmoidf_(mo[k]);
    }
    int jreg[16];
    {
        const int4* cr = (const int4*)(conn + ((size_t)nc * kC + c) * kK);
        #pragma unroll
        for (int q = 0; q < 4; ++q) {
            int4 v = cr[q];
            jreg[4*q] = v.x; jreg[4*q+1] = v.y; jreg[4*q+2] = v.z; jreg[4*q+3] = v.w;
        }
    }
    const float decay = sigmoidf_(mo[kK + kKB]);
    float pnew[32];
    {
        const float4* p4 = (const float4*)(prim + nbase * kD);
        if (poff == 28) {
            const float4* d4 = (const float4*)(mo + 28);
            #pragma unroll
            for (int q = 0; q < 8; ++q) {
                float4 v = p4[q], w = d4[q];
                pnew[4*q]   = v.x + w.x;
                pnew[4*q+1] = v.y + w.y;
                pnew[4*q+2] = v.z + w.z;
                pnew[4*q+3] = v.w + w.w;
            }
        } else {
            #pragma unroll
            for (int q = 0; q < 8; ++q) {
                float4 v = p4[q];
                pnew[4*q]   = v.x + mo[25 + 4*q];
                pnew[4*q+1] = v.y + mo[25 + 4*q + 1];
                pnew[4*q+2] = v.z + mo[25 + 4*q + 2];
                pnew[4*q+3] = v.w + mo[25 + 4*q + 3];
            }
        }
    }
    __syncthreads();

    // ---- received = sum_k sigmoid(w_conn[k]) * prev_msg[conn[k]] ----
    float recv[32];
    #pragma unroll
    for (int d = 0; d < 32; ++d) recv[d] = 0.f;
    #pragma unroll 1
    for (int k = 0; k < 16; ++k) {
        const float4* row = (const float4*)(slab + jreg[k] * kSLAB);
        const float w = wcon[k];
        #pragma unroll
        for (int q = 0; q < 8; ++q) {
            float4 v = row[q];
            recv[4*q]   += v.x * w;
            recv[4*q+1] += v.y * w;
            recv[4*q+2] += v.z * w;
            recv[4*q+3] += v.w * w;
        }
    }
    // border contributions (neurons 4..19)
    if (c >= kALPHA && c < kALPHA + kB) {
        const int j = c - kALPHA;
        const int* br = bconn + ((size_t)nc * kB + j) * kKB;
        #pragma unroll 1
        for (int kb = 0; kb < kKB; ++kb) {
            int g = br[kb];
            int nc2 = g >> 4;
            int c2 = kALPHA + (g & 15);
            const float4* src = (const float4*)(pmsg + (((size_t)b * kNC + nc2) * kC + c2) * kD);
            float w = sigmoidf_(mo[kK + kb]);
            #pragma unroll
            for (int q = 0; q < 8; ++q) {
                float4 v = src[q];
                recv[4*q]   += v.x * w;
                recv[4*q+1] += v.y * w;
                recv[4*q+2] += v.z * w;
                recv[4*q+3] += v.w * w;
            }
        }
    }
    // cc injection (neurons 0..3)
    if (c < kALPHA) {
        const float* src = cc + (size_t)b * (kNC * kD) + nc * kD;
        #pragma unroll
        for (int d = 0; d < 32; ++d) recv[d] += src[d];
    }

    // ---- state MLP: s_in = [h(32), recv(32), pnew(32), decay] ----
    float dh[32];
    #pragma unroll
    for (int o = 0; o < 32; ++o) dh[o] = sb2s[o];
    #pragma unroll 2
    for (int hh = 0; hh < kHS; ++hh) {
        const float4* w4 = (const float4*)(w1s + hh * kW1S);
        float p0 = 0.f, p1 = 0.f, p2 = 0.f, p3 = 0.f;
        #pragma unroll
        for (int q = 0; q < 8; ++q) {
            float4 wv = w4[q];
            p0 += hreg[4*q] * wv.x;   p1 += hreg[4*q+1] * wv.y;
            p2 += hreg[4*q+2] * wv.z; p3 += hreg[4*q+3] * wv.w;
        }
        #pragma unroll
        for (int q = 0; q < 8; ++q) {
            float4 wv = w4[8+q];
            p0 += recv[4*q] * wv.x;   p1 += recv[4*q+1] * wv.y;
            p2 += recv[4*q+2] * wv.z; p3 += recv[4*q+3] * wv.w;
        }
        #pragma unroll
        for (int q = 0; q < 8; ++q) {
            float4 wv = w4[16+q];
            p0 += pnew[4*q] * wv.x;   p1 += pnew[4*q+1] * wv.y;
            p2 += pnew[4*q+2] * wv.z; p3 += pnew[4*q+3] * wv.w;
        }
        float acc = sb1s[hh] + ((p0 + p1) + (p2 + p3)) + decay * w1s[hh * kW1S + 96];
        const float s = tanhf(acc);
        const float4* w2r = (const float4*)(w2ts + hh * kD);
        #pragma unroll
        for (int q = 0; q < 8; ++q) {
            float4 wv = w2r[q];
            dh[4*q]   += s * wv.x;
            dh[4*q+1] += s * wv.y;
            dh[4*q+2] += s * wv.z;
            dh[4*q+3] += s * wv.w;
        }
    }
    float hnew[32];
    #pragma unroll
    for (int d = 0; d < 32; ++d) hnew[d] = decay * hreg[d] + (1.f - decay) * tanhf(dh[d]);

    // write h_new
    {
        float4* dst = (float4*)(out + kO1 + nbase * kD);
        #pragma unroll
        for (int q = 0; q < 8; ++q)
            dst[q] = make_float4(hnew[4*q], hnew[4*q+1], hnew[4*q+2], hnew[4*q+3]);
    }

    // ---- msg MLP: m_in = [h_new(32), recv(32), nid(32)] ----
    float nidr[32];
    {
        const float4* src = (const float4*)(nid + ((size_t)nc * kC + c) * kD);
        #pragma unroll
        for (int q = 0; q < 8; ++q) {
            float4 v = src[q];
            nidr[4*q] = v.x; nidr[4*q+1] = v.y; nidr[4*q+2] = v.z; nidr[4*q+3] = v.w;
        }
    }
    float mm[32];
    #pragma unroll
    for (int o = 0; o < 32; ++o) mm[o] = mb2s[o];
    #pragma unroll 2
    for (int hh = 0; hh < kHM; ++hh) {
        const float4* w4 = (const float4*)(mw1s + hh * 96);
        float p0 = 0.f, p1 = 0.f, p2 = 0.f, p3 = 0.f;
        #pragma unroll
        for (int q = 0; q < 8; ++q) {
            float4 wv = w4[q];
            p0 += hnew[4*q] * wv.x;   p1 += hnew[4*q+1] * wv.y;
            p2 += hnew[4*q+2] * wv.z; p3 += hnew[4*q+3] * wv.w;
        }
        #pragma unroll
        for (int q = 0; q < 8; ++q) {
            float4 wv = w4[8+q];
            p0 += recv[4*q] * wv.x;   p1 += recv[4*q+1] * wv.y;
            p2 += recv[4*q+2] * wv.z; p3 += recv[4*q+3] * wv.w;
        }
        #pragma unroll
        for (int q = 0; q < 8; ++q) {
            float4 wv = w4[16+q];
            p0 += nidr[4*q] * wv.x;   p1 += nidr[4*q+1] * wv.y;
            p2 += nidr[4*q+2] * wv.z; p3 += nidr[4*q+3] * wv.w;
        }
        const float s = tanhf(mb1s[hh] + ((p0 + p1) + (p2 + p3)));
        const float4* w2r = (const float4*)(mw2ts + hh * kD);
        #pragma unroll
        for (int q = 0; q < 8; ++q) {
            float4 wv = w2r[q];
            mm[4*q]   += s * wv.x;
            mm[4*q+1] += s * wv.y;
            mm[4*q+2] += s * wv.z;
            mm[4*q+3] += s * wv.w;
        }
    }
    float msgr[32];
    #pragma unroll
    for (int d = 0; d < 32; ++d) msgr[d] = tanhf(mm[d]);

    __syncthreads();   // everyone done reading prev_messages from slab
    {
        float4* row = (float4*)(slab + c * kSLAB);
        #pragma unroll
        for (int q = 0; q < 8; ++q)
            row[q] = make_float4(msgr[4*q], msgr[4*q+1], msgr[4*q+2], msgr[4*q+3]);
    }
    __syncthreads();

    // ---- hebbian update: corr[k] = (msg . msg[conn[k]]) / D ----
    {
        const float* hb = hebin + nbase * kK;
        float* dst = out + kO3 + nbase * kK;
        #pragma unroll 1
        for (int k = 0; k < 16; ++k) {
            const float4* row = (const float4*)(slab + jreg[k] * kSLAB);
            float dot = 0.f;
            #pragma unroll
            for (int q = 0; q < 8; ++q) {
                float4 v = row[q];
                dot += msgr[4*q] * v.x + msgr[4*q+1] * v.y
                     + msgr[4*q+2] * v.z + msgr[4*q+3] * v.w;
            }
            dst[k] = 0.9f * hb[k] + 0.1f * (dot * (1.0f / 32.0f));
        }
    }
    // msg output, coalesced via LDS
    {
        float4* dst = (float4*)(out + kO2 + cellrow * kD);
        for (int i = c; i < (kC * kD) / 4; i += kC)
            dst[i] = *(const float4*)&slab[(i >> 3) * kSLAB + ((i & 7) << 2)];
    }
    // readout: mean of last ALPHA=4 neurons' msg
    if (c < kD) {
        float s = 0.25f * (slab[(kC-4)*kSLAB + c] + slab[(kC-3)*kSLAB + c] +
                           slab[(kC-2)*kSLAB + c] + slab[(kC-1)*kSLAB + c]);
        out[(size_t)b * (kNC * kD) + nc * kD + c] = s;
    }
}

extern "C" void kernel_launch(void* const* d_in, const int* in_sizes, int n_in,
                              void* d_out, int out_size, void* d_ws, size_t ws_size,
                              hipStream_t stream)
{
    const float* cc    = (const float*)d_in[0];
    const float* h     = (const float*)d_in[1];
    const float* pmsg  = (const float*)d_in[2];
    const float* dlog  = (const float*)d_in[3];
    const float* prim  = (const float*)d_in[4];
    const float* heb   = (const float*)d_in[5];
    const float* sw1   = (const float*)d_in[6];
    const float* sb1   = (const float*)d_in[7];
    const float* sw2   = (const float*)d_in[8];
    const float* sb2   = (const float*)d_in[9];
    const float* mw1   = (const float*)d_in[10];
    const float* mb1   = (const float*)d_in[11];
    const float* mw2   = (const float*)d_in[12];
    const float* mb2   = (const float*)d_in[13];
    const float* modw1 = (const float*)d_in[14];
    const float* modb1 = (const float*)d_in[15];
    const float* modw2 = (const float*)d_in[16];
    const float* modb2 = (const float*)d_in[17];
    const float* nid   = (const float*)d_in[18];
    const int*   conn  = (const int*)d_in[19];
    const int*   bconn = (const int*)d_in[20];
    float* out = (float*)d_out;
    float* modout = (float*)d_ws;

    // padded modout rows (60 words, prim-delta 16B-aligned at word 28) if the
    // workspace allows; otherwise fall back to the original tight 57 layout.
    int mos = 57, poff = 25;
    if (ws_size >= (size_t)kBS * kN * 60 * sizeof(float)) { mos = 60; poff = 28; }

    mod_mlp_kernel<<<kN / 4, 256, 0, stream>>>(heb, h, dlog, prim, nid,
                                               modw1, modb1, modw2, modb2,
                                               modout, mos, poff);
    cell_kernel<<<dim3(kNC, kBS), kC, 0, stream>>>(cc, h, pmsg, prim, heb, nid,
                                                   sw1, sb1, sw2, sb2,
                                                   mw1, mb1, mw2, mb2,
                                                   conn, bconn, modout, out,
                                                   mos, poff);
}

// Round 2
// 756.161 us; speedup vs baseline: 1.2621x; 1.0131x over previous
//
#include <hip/hip_runtime.h>
#include <cstdint>
#include <cstddef>

constexpr int kBS = 8;
constexpr int kNC = 64;
constexpr int kC = 256;
constexpr int kD = 32;
constexpr int kK = 16;
constexpr int kKB = 8;
constexpr int kALPHA = 4;
constexpr int kB = 16;
constexpr int kHS = 64;
constexpr int kHM = 64;
constexpr int kHMOD = 32;
constexpr int kN = kNC * kC;               // 16384
constexpr int kMODIN = kK + 3 * kD + 1;    // 113
constexpr int kMODOUT = kK + kKB + 1 + kD; // 57
constexpr int kXS = 116;                   // mod-x LDS row stride (464B, 16B mult)
constexpr int kWS = 116;                   // mod-W1 LDS row stride
constexpr int kW1S = 100;                  // state w1 LDS row stride (400B, 16B mult)
constexpr int kSLAB = 36;                  // slab row stride (144B, 16B mult)

constexpr size_t kO1 = (size_t)kBS * kNC * kD;        // readout
constexpr size_t kO2 = kO1 + (size_t)kBS * kN * kD;   // + h_new
constexpr size_t kO3 = kO2 + (size_t)kBS * kN * kD;   // + msg

__device__ __forceinline__ float sigmoidf_(float x) {
    return 1.0f / (1.0f + __expf(-x));
}
__device__ __forceinline__ float rdlane(float v, int l) {
    return __int_as_float(__builtin_amdgcn_readlane(__float_as_int(v), l));
}

// ---------------- Kernel A: per-neuron modulation MLP --------------------
// 256 threads = 4 independent waves, one neuron per wave.
// W1 (14.5KB/neuron) is staged into LDS with COALESCED float4 global loads
// (read exactly once from HBM — the per-lane strided dword stream thrashed
// L1/L2 and re-fetched W1 many times). Compute then reads per-lane rows from
// padded LDS (<=4-way conflict on 29 reads) with broadcast x reads.
// Layer 2 pulls hidden values cross-lane via v_readlane; W2 read from global
// coalesced (consumed immediately, no reuse -> no thrash).
// No __syncthreads needed: each wave touches only its own LDS buffers.
__global__ __launch_bounds__(256) void mod_mlp_kernel(
    const float* __restrict__ heb, const float* __restrict__ h,
    const float* __restrict__ dlog, const float* __restrict__ prim,
    const float* __restrict__ nid,
    const float* __restrict__ mw1, const float* __restrict__ mb1,
    const float* __restrict__ mw2, const float* __restrict__ mb2,
    float* __restrict__ modout, int mos, int poff)
{
    const int wv = threadIdx.x >> 6;
    const int lane = threadIdx.x & 63;
    const int n = (blockIdx.x << 2) | wv;

    __shared__ __align__(16) float xs[4][kBS * kXS];      // 14848 B
    __shared__ __align__(16) float w1sh[4][kHMOD * kWS];  // 59392 B
    float* xw  = xs[wv];
    float* w1s = w1sh[wv];

    // ---- stage W1 coalesced (904 float4 = 14464 B contiguous) ----
    {
        const float4* w1g4 = (const float4*)(mw1 + (size_t)n * (kHMOD * kMODIN));
        for (int t = lane; t < (kHMOD * kMODIN) / 4; t += 64) {
            float4 v = w1g4[t];
            int f = t << 2;
            #pragma unroll
            for (int e = 0; e < 4; ++e) {
                int fe = f + e;
                int r = fe / kMODIN;
                int col = fe - r * kMODIN;
                float val = (e == 0) ? v.x : (e == 1) ? v.y : (e == 2) ? v.z : v.w;
                w1s[r * kWS + col] = val;
            }
        }
    }

    // ---- stage mod-input vectors for all 8 batches ----
    for (int t = lane; t < kBS * kMODIN; t += 64) {
        int b = t / kMODIN;
        int i = t - b * kMODIN;
        size_t nb = (size_t)b * kN + n;
        float v;
        if (i < kK)                 v = heb[nb * kK + i];
        else if (i < kK + kD)       v = h[nb * kD + (i - kK)];
        else if (i == kK + kD)      v = dlog[nb];
        else if (i < kK + 2*kD + 1) v = prim[nb * kD + (i - (kK + kD + 1))];
        else                        v = nid[(size_t)n * kD + (i - (kK + 2*kD + 1))];
        xw[b * kXS + i] = v;
    }
    // same-wave LDS RAW: compiler inserts lgkmcnt wait; no barrier needed.

    // ---- layer 1: lane computes hid[b][hh] for hh=lane&31, 4 batches ----
    const int hh = lane & 31;
    const int bh = lane >> 5;
    const float* wr = w1s + hh * kWS;
    float a0 = 0.f, a1 = 0.f, a2 = 0.f, a3 = 0.f;
    #pragma unroll 4
    for (int q = 0; q < 28; ++q) {
        const float4 wv4 = *(const float4*)(wr + 4*q);
        const float4 x0 = *(const float4*)(xw + (bh+0) * kXS + 4*q);
        const float4 x1 = *(const float4*)(xw + (bh+2) * kXS + 4*q);
        const float4 x2 = *(const float4*)(xw + (bh+4) * kXS + 4*q);
        const float4 x3 = *(const float4*)(xw + (bh+6) * kXS + 4*q);
        a0 += wv4.x*x0.x + wv4.y*x0.y + wv4.z*x0.z + wv4.w*x0.w;
        a1 += wv4.x*x1.x + wv4.y*x1.y + wv4.z*x1.z + wv4.w*x1.w;
        a2 += wv4.x*x2.x + wv4.y*x2.y + wv4.z*x2.z + wv4.w*x2.w;
        a3 += wv4.x*x3.x + wv4.y*x3.y + wv4.z*x3.z + wv4.w*x3.w;
    }
    {
        float w112 = wr[112];
        a0 += w112 * xw[(bh+0)*kXS + 112];
        a1 += w112 * xw[(bh+2)*kXS + 112];
        a2 += w112 * xw[(bh+4)*kXS + 112];
        a3 += w112 * xw[(bh+6)*kXS + 112];
    }
    const float bb = mb1[(size_t)n * kHMOD + hh];
    float h0 = tanhf(a0 + bb);   // b = bh+0
    float h1 = tanhf(a1 + bb);   // b = bh+2
    float h2 = tanhf(a2 + bb);   // b = bh+4
    float h3 = tanhf(a3 + bb);   // b = bh+6

    // ---- layer 2: lane = output o; hid[b][hh] via readlane ----
    const int o = (lane < kMODOUT) ? lane : (kMODOUT - 1);
    const float* w2g = mw2 + (size_t)n * (kHMOD * kMODOUT);
    float ob0=0.f, ob1=0.f, ob2=0.f, ob3=0.f, ob4=0.f, ob5=0.f, ob6=0.f, ob7=0.f;
    #pragma unroll
    for (int hx = 0; hx < kHMOD; ++hx) {
        float w = w2g[hx * kMODOUT + o];
        ob0 += rdlane(h0, hx)      * w;   // b=0 lives in lanes 0..31
        ob1 += rdlane(h0, hx + 32) * w;   // b=1 lives in lanes 32..63
        ob2 += rdlane(h1, hx)      * w;
        ob3 += rdlane(h1, hx + 32) * w;
        ob4 += rdlane(h2, hx)      * w;
        ob5 += rdlane(h2, hx + 32) * w;
        ob6 += rdlane(h3, hx)      * w;
        ob7 += rdlane(h3, hx + 32) * w;
    }
    if (lane < kMODOUT) {
        const float bo = mb2[(size_t)n * kMODOUT + o];
        const int oo = (o < 25) ? o : (o + (poff - 25));
        modout[((size_t)0 * kN + n) * mos + oo] = ob0 + bo;
        modout[((size_t)1 * kN + n) * mos + oo] = ob1 + bo;
        modout[((size_t)2 * kN + n) * mos + oo] = ob2 + bo;
        modout[((size_t)3 * kN + n) * mos + oo] = ob3 + bo;
        modout[((size_t)4 * kN + n) * mos + oo] = ob4 + bo;
        modout[((size_t)5 * kN + n) * mos + oo] = ob5 + bo;
        modout[((size_t)6 * kN + n) * mos + oo] = ob6 + bo;
        modout[((size_t)7 * kN + n) * mos + oo] = ob7 + bo;
    }
}

// ---------------- Kernel B: per-cell message passing + state/msg MLPs -----
// 512 threads = TWO cells per block (same b, nc pair), sharing one LDS-staged
// weight set. 141KB LDS -> 1 block/CU but 8 waves = 2 waves/SIMD (round-1 had
// only 1 wave/SIMD -> latency-bound at VALUBusy 33%). Weight staging traffic
// also halves.
__global__ __launch_bounds__(512, 2) void cell_kernel(
    const float* __restrict__ cc, const float* __restrict__ hin,
    const float* __restrict__ pmsg, const float* __restrict__ prim,
    const float* __restrict__ hebin, const float* __restrict__ nid,
    const float* __restrict__ sw1, const float* __restrict__ sb1,
    const float* __restrict__ sw2, const float* __restrict__ sb2,
    const float* __restrict__ mw1g, const float* __restrict__ mb1g,
    const float* __restrict__ mw2g, const float* __restrict__ mb2g,
    const int* __restrict__ conn, const int* __restrict__ bconn,
    const float* __restrict__ modout, float* __restrict__ out,
    int mos, int poff)
{
    const int half = threadIdx.x >> 8;
    const int c    = threadIdx.x & 255;
    const int nc   = (blockIdx.x << 1) | half;
    const int b    = blockIdx.y;

    __shared__ __align__(16) float slab2[2][kC * kSLAB];  // 73728 B
    __shared__ __align__(16) float w1s[kHS * kW1S];       // 25600 B
    __shared__ __align__(16) float w2ts[kHS * kD];        //  8192 B
    __shared__ __align__(16) float mw1s[kHM * 96];        // 24576 B
    __shared__ __align__(16) float mw2ts[kHM * kD];       //  8192 B
    __shared__ float sb1s[kHS], sb2s[kD], mb1s[kHM], mb2s[kD];
    // total ~141 KB of 160 KB -> 1 block/CU, 8 waves

    float* slab = slab2[half];
    const size_t cellrow = ((size_t)b * kNC + nc) * kC;
    const size_t nbase   = cellrow + c;

    // ---- stage weights (whole block cooperates) ----
    for (int idx = threadIdx.x; idx < kHS * 97; idx += 512) {
        int r = idx / 97, ci = idx - r * 97;
        w1s[r * kW1S + ci] = sw1[idx];
    }
    for (int idx = threadIdx.x; idx < kHM * 96; idx += 512) mw1s[idx] = mw1g[idx];
    for (int idx = threadIdx.x; idx < kHS * kD; idx += 512) {  // sw2 is [o=32][hh=64]
        int o2 = idx >> 6, h2 = idx & 63;
        w2ts[h2 * kD + o2] = sw2[idx];
    }
    for (int idx = threadIdx.x; idx < kHM * kD; idx += 512) {
        int o2 = idx >> 6, h2 = idx & 63;
        mw2ts[h2 * kD + o2] = mw2g[idx];
    }
    if (threadIdx.x < kHS)  sb1s[threadIdx.x] = sb1[threadIdx.x];
    if (threadIdx.x < kD)   sb2s[threadIdx.x] = sb2[threadIdx.x];
    if (threadIdx.x >= 64 && threadIdx.x < 64 + kHM) mb1s[threadIdx.x - 64] = mb1g[threadIdx.x - 64];
    if (threadIdx.x >= 128 && threadIdx.x < 128 + kD) mb2s[threadIdx.x - 128] = mb2g[threadIdx.x - 128];

    // ---- stage this cell's prev_messages (coalesced, float4) ----
    {
        const float4* s4 = (const float4*)(pmsg + cellrow * kD);
        for (int i = c; i < (kC * kD) / 4; i += kC) {
            float4 v = s4[i];
            *(float4*)&slab[(i >> 3) * kSLAB + ((i & 7) << 2)] = v;
        }
    }

    // ---- per-thread loads (overlap with staging) ----
    float hreg[32];
    {
        const float4* src = (const float4*)(hin + nbase * kD);
        #pragma unroll
        for (int q = 0; q < 8; ++q) {
            float4 v = src[q];
            hreg[4*q] = v.x; hreg[4*q+1] = v.y; hreg[4*q+2] = v.z; hreg[4*q+3] = v.w;
        }
    }
    const float* mo = modout + nbase * mos;
    float wcon[16];
    if (poff == 28) {
        const float4* m4 = (const float4*)mo;
        float4 va = m4[0], vb = m4[1], vc = m4[2], vd = m4[3];
        wcon[0]=sigmoidf_(va.x);  wcon[1]=sigmoidf_(va.y);  wcon[2]=sigmoidf_(va.z);  wcon[3]=sigmoidf_(va.w);
        wcon[4]=sigmoidf_(vb.x);  wcon[5]=sigmoidf_(vb.y);  wcon[6]=sigmoidf_(vb.z);  wcon[7]=sigmoidf_(vb.w);
        wcon[8]=sigmoidf_(vc.x);  wcon[9]=sigmoidf_(vc.y);  wcon[10]=sigmoidf_(vc.z); wcon[11]=sigmoidf_(vc.w);
        wcon[12]=sigmoidf_(vd.x); wcon[13]=sigmoidf_(vd.y); wcon[14]=sigmoidf_(vd.z); wcon[15]=sigmoidf_(vd.w);
    } else {
        #pragma unroll
        for (int k = 0; k < 16; ++k) wcon[k] = sigmoidf_(mo[k]);
    }
    int jreg[16];
    {
        const int4* cr = (const int4*)(conn + ((size_t)nc * kC + c) * kK);
        #pragma unroll
        for (int q = 0; q < 4; ++q) {
            int4 v = cr[q];
            jreg[4*q] = v.x; jreg[4*q+1] = v.y; jreg[4*q+2] = v.z; jreg[4*q+3] = v.w;
        }
    }
    const float decay = sigmoidf_(mo[kK + kKB]);
    float pnew[32];
    {
        const float4* p4 = (const float4*)(prim + nbase * kD);
        if (poff == 28) {
            const float4* d4 = (const float4*)(mo + 28);
            #pragma unroll
            for (int q = 0; q < 8; ++q) {
                float4 v = p4[q], w = d4[q];
                pnew[4*q]   = v.x + w.x;
                pnew[4*q+1] = v.y + w.y;
                pnew[4*q+2] = v.z + w.z;
                pnew[4*q+3] = v.w + w.w;
            }
        } else {
            #pragma unroll
            for (int q = 0; q < 8; ++q) {
                float4 v = p4[q];
                pnew[4*q]   = v.x + mo[25 + 4*q];
                pnew[4*q+1] = v.y + mo[25 + 4*q + 1];
                pnew[4*q+2] = v.z + mo[25 + 4*q + 2];
                pnew[4*q+3] = v.w + mo[25 + 4*q + 3];
            }
        }
    }
    __syncthreads();

    // ---- received = sum_k sigmoid(w_conn[k]) * prev_msg[conn[k]] ----
    float recv[32];
    #pragma unroll
    for (int d = 0; d < 32; ++d) recv[d] = 0.f;
    #pragma unroll 1
    for (int k = 0; k < 16; ++k) {
        const float4* row = (const float4*)(slab + jreg[k] * kSLAB);
        const float w = wcon[k];
        #pragma unroll
        for (int q = 0; q < 8; ++q) {
            float4 v = row[q];
            recv[4*q]   += v.x * w;
            recv[4*q+1] += v.y * w;
            recv[4*q+2] += v.z * w;
            recv[4*q+3] += v.w * w;
        }
    }
    // border contributions (neurons 4..19)
    if (c >= kALPHA && c < kALPHA + kB) {
        const int j = c - kALPHA;
        const int* br = bconn + ((size_t)nc * kB + j) * kKB;
        #pragma unroll 1
        for (int kb = 0; kb < kKB; ++kb) {
            int g = br[kb];
            int nc2 = g >> 4;
            int c2 = kALPHA + (g & 15);
            const float4* src = (const float4*)(pmsg + (((size_t)b * kNC + nc2) * kC + c2) * kD);
            float w = sigmoidf_(mo[kK + kb]);
            #pragma unroll
            for (int q = 0; q < 8; ++q) {
                float4 v = src[q];
                recv[4*q]   += v.x * w;
                recv[4*q+1] += v.y * w;
                recv[4*q+2] += v.z * w;
                recv[4*q+3] += v.w * w;
            }
        }
    }
    // cc injection (neurons 0..3)
    if (c < kALPHA) {
        const float* src = cc + (size_t)b * (kNC * kD) + nc * kD;
        #pragma unroll
        for (int d = 0; d < 32; ++d) recv[d] += src[d];
    }

    // ---- state MLP: s_in = [h(32), recv(32), pnew(32), decay] ----
    float dh[32];
    #pragma unroll
    for (int o = 0; o < 32; ++o) dh[o] = sb2s[o];
    #pragma unroll 2
    for (int hh = 0; hh < kHS; ++hh) {
        const float4* w4 = (const float4*)(w1s + hh * kW1S);
        float p0 = 0.f, p1 = 0.f, p2 = 0.f, p3 = 0.f;
        #pragma unroll
        for (int q = 0; q < 8; ++q) {
            float4 wv = w4[q];
            p0 += hreg[4*q] * wv.x;   p1 += hreg[4*q+1] * wv.y;
            p2 += hreg[4*q+2] * wv.z; p3 += hreg[4*q+3] * wv.w;
        }
        #pragma unroll
        for (int q = 0; q < 8; ++q) {
            float4 wv = w4[8+q];
            p0 += recv[4*q] * wv.x;   p1 += recv[4*q+1] * wv.y;
            p2 += recv[4*q+2] * wv.z; p3 += recv[4*q+3] * wv.w;
        }
        #pragma unroll
        for (int q = 0; q < 8; ++q) {
            float4 wv = w4[16+q];
            p0 += pnew[4*q] * wv.x;   p1 += pnew[4*q+1] * wv.y;
            p2 += pnew[4*q+2] * wv.z; p3 += pnew[4*q+3] * wv.w;
        }
        float acc = sb1s[hh] + ((p0 + p1) + (p2 + p3)) + decay * w1s[hh * kW1S + 96];
        const float s = tanhf(acc);
        const float4* w2r = (const float4*)(w2ts + hh * kD);
        #pragma unroll
        for (int q = 0; q < 8; ++q) {
            float4 wv = w2r[q];
            dh[4*q]   += s * wv.x;
            dh[4*q+1] += s * wv.y;
            dh[4*q+2] += s * wv.z;
            dh[4*q+3] += s * wv.w;
        }
    }
    float hnew[32];
    #pragma unroll
    for (int d = 0; d < 32; ++d) hnew[d] = decay * hreg[d] + (1.f - decay) * tanhf(dh[d]);

    // write h_new
    {
        float4* dst = (float4*)(out + kO1 + nbase * kD);
        #pragma unroll
        for (int q = 0; q < 8; ++q)
            dst[q] = make_float4(hnew[4*q], hnew[4*q+1], hnew[4*q+2], hnew[4*q+3]);
    }

    // ---- msg MLP: m_in = [h_new(32), recv(32), nid(32)] ----
    float nidr[32];
    {
        const float4* src = (const float4*)(nid + ((size_t)nc * kC + c) * kD);
        #pragma unroll
        for (int q = 0; q < 8; ++q) {
            float4 v = src[q];
            nidr[4*q] = v.x; nidr[4*q+1] = v.y; nidr[4*q+2] = v.z; nidr[4*q+3] = v.w;
        }
    }
    float mm[32];
    #pragma unroll
    for (int o = 0; o < 32; ++o) mm[o] = mb2s[o];
    #pragma unroll 2
    for (int hh = 0; hh < kHM; ++hh) {
        const float4* w4 = (const float4*)(mw1s + hh * 96);
        float p0 = 0.f, p1 = 0.f, p2 = 0.f, p3 = 0.f;
        #pragma unroll
        for (int q = 0; q < 8; ++q) {
            float4 wv = w4[q];
            p0 += hnew[4*q] * wv.x;   p1 += hnew[4*q+1] * wv.y;
            p2 += hnew[4*q+2] * wv.z; p3 += hnew[4*q+3] * wv.w;
        }
        #pragma unroll
        for (int q = 0; q < 8; ++q) {
            float4 wv = w4[8+q];
            p0 += recv[4*q] * wv.x;   p1 += recv[4*q+1] * wv.y;
            p2 += recv[4*q+2] * wv.z; p3 += recv[4*q+3] * wv.w;
        }
        #pragma unroll
        for (int q = 0; q < 8; ++q) {
            float4 wv = w4[16+q];
            p0 += nidr[4*q] * wv.x;   p1 += nidr[4*q+1] * wv.y;
            p2 += nidr[4*q+2] * wv.z; p3 += nidr[4*q+3] * wv.w;
        }
        const float s = tanhf(mb1s[hh] + ((p0 + p1) + (p2 + p3)));
        const float4* w2r = (const float4*)(mw2ts + hh * kD);
        #pragma unroll
        for (int q = 0; q < 8; ++q) {
            float4 wv = w2r[q];
            mm[4*q]   += s * wv.x;
            mm[4*q+1] += s * wv.y;
            mm[4*q+2] += s * wv.z;
            mm[4*q+3] += s * wv.w;
        }
    }
    float msgr[32];
    #pragma unroll
    for (int d = 0; d < 32; ++d) msgr[d] = tanhf(mm[d]);

    __syncthreads();   // everyone done reading prev_messages from slabs
    {
        float4* row = (float4*)(slab + c * kSLAB);
        #pragma unroll
        for (int q = 0; q < 8; ++q)
            row[q] = make_float4(msgr[4*q], msgr[4*q+1], msgr[4*q+2], msgr[4*q+3]);
    }
    __syncthreads();

    // ---- hebbian update: corr[k] = (msg . msg[conn[k]]) / D ----
    {
        const float* hb = hebin + nbase * kK;
        float* dst = out + kO3 + nbase * kK;
        #pragma unroll 1
        for (int k = 0; k < 16; ++k) {
            const float4* row = (const float4*)(slab + jreg[k] * kSLAB);
            float dot = 0.f;
            #pragma unroll
            for (int q = 0; q < 8; ++q) {
                float4 v = row[q];
                dot += msgr[4*q] * v.x + msgr[4*q+1] * v.y
                     + msgr[4*q+2] * v.z + msgr[4*q+3] * v.w;
            }
            dst[k] = 0.9f * hb[k] + 0.1f * (dot * (1.0f / 32.0f));
        }
    }
    // msg output, coalesced via LDS
    {
        float4* dst = (float4*)(out + kO2 + cellrow * kD);
        for (int i = c; i < (kC * kD) / 4; i += kC)
            dst[i] = *(const float4*)&slab[(i >> 3) * kSLAB + ((i & 7) << 2)];
    }
    // readout: mean of last ALPHA=4 neurons' msg
    if (c < kD) {
        float s = 0.25f * (slab[(kC-4)*kSLAB + c] + slab[(kC-3)*kSLAB + c] +
                           slab[(kC-2)*kSLAB + c] + slab[(kC-1)*kSLAB + c]);
        out[(size_t)b * (kNC * kD) + nc * kD + c] = s;
    }
}

extern "C" void kernel_launch(void* const* d_in, const int* in_sizes, int n_in,
                              void* d_out, int out_size, void* d_ws, size_t ws_size,
                              hipStream_t stream)
{
    const float* cc    = (const float*)d_in[0];
    const float* h     = (const float*)d_in[1];
    const float* pmsg  = (const float*)d_in[2];
    const float* dlog  = (const float*)d_in[3];
    const float* prim  = (const float*)d_in[4];
    const float* heb   = (const float*)d_in[5];
    const float* sw1   = (const float*)d_in[6];
    const float* sb1   = (const float*)d_in[7];
    const float* sw2   = (const float*)d_in[8];
    const float* sb2   = (const float*)d_in[9];
    const float* mw1   = (const float*)d_in[10];
    const float* mb1   = (const float*)d_in[11];
    const float* mw2   = (const float*)d_in[12];
    const float* mb2   = (const float*)d_in[13];
    const float* modw1 = (const float*)d_in[14];
    const float* modb1 = (const float*)d_in[15];
    const float* modw2 = (const float*)d_in[16];
    const float* modb2 = (const float*)d_in[17];
    const float* nid   = (const float*)d_in[18];
    const int*   conn  = (const int*)d_in[19];
    const int*   bconn = (const int*)d_in[20];
    float* out = (float*)d_out;
    float* modout = (float*)d_ws;

    int mos = 57, poff = 25;
    if (ws_size >= (size_t)kBS * kN * 60 * sizeof(float)) { mos = 60; poff = 28; }

    mod_mlp_kernel<<<kN / 4, 256, 0, stream>>>(heb, h, dlog, prim, nid,
                                               modw1, modb1, modw2, modb2,
                                               modout, mos, poff);
    cell_kernel<<<dim3(kNC / 2, kBS), 512, 0, stream>>>(cc, h, pmsg, prim, heb, nid,
                                                        sw1, sb1, sw2, sb2,
                                                        mw1, mb1, mw2, mb2,
                                                        conn, bconn, modout, out,
                                                        mos, poff);
}

// Round 4
// 729.135 us; speedup vs baseline: 1.3088x; 1.0371x over previous
//
#include <hip/hip_runtime.h>
#include <cstdint>
#include <cstddef>

constexpr int kBS = 8;
constexpr int kNC = 64;
constexpr int kC = 256;
constexpr int kD = 32;
constexpr int kK = 16;
constexpr int kKB = 8;
constexpr int kALPHA = 4;
constexpr int kB = 16;
constexpr int kHS = 64;
constexpr int kHM = 64;
constexpr int kHMOD = 32;
constexpr int kN = kNC * kC;               // 16384
constexpr int kMODIN = kK + 3 * kD + 1;    // 113
constexpr int kMODOUT = kK + kKB + 1 + kD; // 57
constexpr int kXS = 116;                   // mod-x LDS row stride (16B mult)
constexpr int kWS = 116;                   // mod-W1 LDS row stride
constexpr int kSLAB = 36;                  // slab row stride (144B, 16B mult)
constexpr int kW2TS = 36;                  // transposed-W2 LDS row stride

constexpr size_t kO1 = (size_t)kBS * kNC * kD;        // readout
constexpr size_t kO2 = kO1 + (size_t)kBS * kN * kD;   // + h_new
constexpr size_t kO3 = kO2 + (size_t)kBS * kN * kD;   // + msg

__device__ __forceinline__ float sigmoidf_(float x) {
    return 1.0f / (1.0f + __expf(-x));
}

// ---------------- Kernel A: per-neuron modulation MLP --------------------
// ONE NEURON PER 256-THREAD BLOCK. Thread = (b, hh) exactly covers 8x32 for
// layer 1. LDS = x (3.7KB) + W1 (14.8KB) + W2 (7.3KB) + hid (1KB) ~ 27KB
// -> ~5 blocks/CU (~60% occupancy) vs round-2's 22.7%. All staging
// coalesced float4; x-staging split into per-region non-divergent loops.
__global__ __launch_bounds__(256) void mod_mlp_kernel(
    const float* __restrict__ heb, const float* __restrict__ h,
    const float* __restrict__ dlog, const float* __restrict__ prim,
    const float* __restrict__ nid,
    const float* __restrict__ mw1, const float* __restrict__ mb1,
    const float* __restrict__ mw2, const float* __restrict__ mb2,
    float* __restrict__ modout, int mos, int poff)
{
    const int n = blockIdx.x;
    const int tid = threadIdx.x;

    __shared__ __align__(16) float xw[kBS * kXS];        // 3712 B
    __shared__ __align__(16) float w1s[kHMOD * kWS];     // 14848 B
    __shared__ __align__(16) float w2s[kHMOD * kMODOUT]; // 7296 B
    __shared__ float hids[kBS * kHMOD];                  // 1024 B

    // ---- stage W1 coalesced (904 float4, 4 rounds) ----
    {
        const float4* w1g4 = (const float4*)(mw1 + (size_t)n * (kHMOD * kMODIN));
        #pragma unroll
        for (int r = 0; r < 4; ++r) {
            int t = tid + 256 * r;
            if (t < (kHMOD * kMODIN) / 4) {
                float4 v = w1g4[t];
                int f = t << 2;
                #pragma unroll
                for (int e = 0; e < 4; ++e) {
                    int fe = f + e;
                    int row = fe / kMODIN;
                    int col = fe - row * kMODIN;
                    float val = (e == 0) ? v.x : (e == 1) ? v.y : (e == 2) ? v.z : v.w;
                    w1s[row * kWS + col] = val;
                }
            }
        }
    }
    // ---- stage W2 coalesced (456 float4, 2 rounds; unpadded rows of 57) ----
    {
        const float4* w2g4 = (const float4*)(mw2 + (size_t)n * (kHMOD * kMODOUT));
        #pragma unroll
        for (int r = 0; r < 2; ++r) {
            int t = tid + 256 * r;
            if (t < (kHMOD * kMODOUT) / 4)
                *(float4*)&w2s[t << 2] = w2g4[t];
        }
    }
    // ---- stage x, per-region tight loops (no divergent 5-way branch) ----
    // layout per batch row: [heb 0..15][h 16..47][dlog 48][prim 49..80][nid 81..112]
    {
        if (tid < kBS * kK) {                // 128: hebbian
            int b = tid >> 4, i = tid & 15;
            xw[b * kXS + i] = heb[((size_t)b * kN + n) * kK + i];
        }
        {
            int b = tid >> 5, d = tid & 31;  // 256 each
            xw[b * kXS + 16 + d] = h[((size_t)b * kN + n) * kD + d];
            xw[b * kXS + 49 + d] = prim[((size_t)b * kN + n) * kD + d];
            xw[b * kXS + 81 + d] = nid[(size_t)n * kD + d];
        }
        if (tid < kBS)
            xw[tid * kXS + 48] = dlog[(size_t)tid * kN + n];
    }
    __syncthreads();

    // ---- layer 1: thread (b,hh) computes one dot of length 113 ----
    {
        const int hh = tid & 31;
        const int b  = tid >> 5;
        const float* wr = w1s + hh * kWS;
        const float* xr = xw + b * kXS;
        float acc = mb1[(size_t)n * kHMOD + hh];
        #pragma unroll 4
        for (int q = 0; q < 28; ++q) {
            float4 wv = *(const float4*)(wr + 4*q);
            float4 xv = *(const float4*)(xr + 4*q);
            acc += wv.x*xv.x + wv.y*xv.y + wv.z*xv.z + wv.w*xv.w;
        }
        acc += wr[112] * xr[112];
        hids[b * kHMOD + hh] = tanhf(acc);
    }
    __syncthreads();

    // ---- layer 2: 456 (b,o) dots of length 32 ----
    for (int t = tid; t < kBS * kMODOUT; t += 256) {
        int b2 = t / kMODOUT;
        int o  = t - b2 * kMODOUT;
        const float* hr = hids + b2 * kHMOD;
        float acc = mb2[(size_t)n * kMODOUT + o];
        #pragma unroll
        for (int hx = 0; hx < kHMOD; ++hx)
            acc += hr[hx] * w2s[hx * kMODOUT + o];
        int oo = (o < 25) ? o : (o + (poff - 25));
        modout[((size_t)b2 * kN + n) * mos + oo] = acc;
    }
}

// ---------------- Kernel B: per-cell message passing + state/msg MLPs -----
// One block per (b,nc); one thread per neuron c. W1 rows are WAVE-UNIFORM ->
// read via the SCALAR pipe (s_load, K$) instead of 24 ds_read_b128
// broadcasts per hh (round-1/2's LDS-issue wall: ~49K LDS cyc/wave).
// W2 matrices are TRANSPOSED into LDS once per block (8 broadcasts/hh) --
// this kills round-0's pathology (32 strided K$ lines per hh). LDS = slab
// 36KB + 2x9KB transposed W2 = 55KB -> both grid-resident blocks fit.
__global__ __launch_bounds__(256) void cell_kernel(
    const float* __restrict__ cc, const float* __restrict__ hin,
    const float* __restrict__ pmsg, const float* __restrict__ prim,
    const float* __restrict__ hebin, const float* __restrict__ nid,
    const float* __restrict__ sw1, const float* __restrict__ sb1,
    const float* __restrict__ sw2, const float* __restrict__ sb2,
    const float* __restrict__ mw1g, const float* __restrict__ mb1g,
    const float* __restrict__ mw2g, const float* __restrict__ mb2g,
    const int* __restrict__ conn, const int* __restrict__ bconn,
    const float* __restrict__ modout, float* __restrict__ out,
    int mos, int poff)
{
    const int nc = blockIdx.x;
    const int b  = blockIdx.y;
    const int c  = threadIdx.x;

    __shared__ __align__(16) float slab[kC * kSLAB];      // 36864 B
    __shared__ __align__(16) float w2ts[kHS * kW2TS];     //  9216 B (state W2^T)
    __shared__ __align__(16) float mw2ts[kHM * kW2TS];    //  9216 B (msg W2^T)
    // total ~55 KB -> 2 blocks/CU (grid gives exactly 2 blocks/CU)

    const size_t cellrow = ((size_t)b * kNC + nc) * kC;
    const size_t nbase   = cellrow + c;

    // ---- stage transposed W2 matrices (coalesced reads; 8-way write
    //      conflict is a one-time staging cost) ----
    for (int idx = c; idx < kHS * kD; idx += kC) {   // sw2 is [o=32][hh=64]
        int o2 = idx >> 6, h2 = idx & 63;
        w2ts[h2 * kW2TS + o2] = sw2[idx];
    }
    for (int idx = c; idx < kHM * kD; idx += kC) {
        int o2 = idx >> 6, h2 = idx & 63;
        mw2ts[h2 * kW2TS + o2] = mw2g[idx];
    }

    // ---- stage this cell's prev_messages (coalesced, float4) ----
    {
        const float4* s4 = (const float4*)(pmsg + cellrow * kD);
        for (int i = c; i < (kC * kD) / 4; i += kC) {
            float4 v = s4[i];
            *(float4*)&slab[(i >> 3) * kSLAB + ((i & 7) << 2)] = v;
        }
    }

    // ---- per-thread loads (overlap with staging) ----
    float hreg[32];
    {
        const float4* src = (const float4*)(hin + nbase * kD);
        #pragma unroll
        for (int q = 0; q < 8; ++q) {
            float4 v = src[q];
            hreg[4*q] = v.x; hreg[4*q+1] = v.y; hreg[4*q+2] = v.z; hreg[4*q+3] = v.w;
        }
    }
    const float* mo = modout + nbase * mos;
    float wcon[16];
    #pragma unroll
    for (int k = 0; k < 16; ++k) wcon[k] = sigmoidf_(mo[k]);
    int jreg[16];
    {
        const int4* cr = (const int4*)(conn + ((size_t)nc * kC + c) * kK);
        #pragma unroll
        for (int q = 0; q < 4; ++q) {
            int4 v = cr[q];
            jreg[4*q] = v.x; jreg[4*q+1] = v.y; jreg[4*q+2] = v.z; jreg[4*q+3] = v.w;
        }
    }
    const float decay = sigmoidf_(mo[kK + kKB]);
    float pnew[32];
    {
        const float4* p4 = (const float4*)(prim + nbase * kD);
        const int pbase = poff;
        #pragma unroll
        for (int q = 0; q < 8; ++q) {
            float4 v = p4[q];
            pnew[4*q]   = v.x + mo[pbase + 4*q];
            pnew[4*q+1] = v.y + mo[pbase + 4*q + 1];
            pnew[4*q+2] = v.z + mo[pbase + 4*q + 2];
            pnew[4*q+3] = v.w + mo[pbase + 4*q + 3];
        }
    }
    __syncthreads();

    // ---- received = sum_k sigmoid(w_conn[k]) * prev_msg[conn[k]] ----
    float recv[32];
    #pragma unroll
    for (int d = 0; d < 32; ++d) recv[d] = 0.f;
    #pragma unroll 1
    for (int k = 0; k < 16; ++k) {
        const float4* row = (const float4*)(slab + jreg[k] * kSLAB);
        const float w = wcon[k];
        #pragma unroll
        for (int q = 0; q < 8; ++q) {
            float4 v = row[q];
            recv[4*q]   += v.x * w;
            recv[4*q+1] += v.y * w;
            recv[4*q+2] += v.z * w;
            recv[4*q+3] += v.w * w;
        }
    }
    // border contributions (neurons 4..19)
    if (c >= kALPHA && c < kALPHA + kB) {
        const int j = c - kALPHA;
        const int* br = bconn + ((size_t)nc * kB + j) * kKB;
        #pragma unroll 1
        for (int kb = 0; kb < kKB; ++kb) {
            int g = br[kb];
            int nc2 = g >> 4;
            int c2 = kALPHA + (g & 15);
            const float4* src = (const float4*)(pmsg + (((size_t)b * kNC + nc2) * kC + c2) * kD);
            float w = sigmoidf_(mo[kK + kb]);
            #pragma unroll
            for (int q = 0; q < 8; ++q) {
                float4 v = src[q];
                recv[4*q]   += v.x * w;
                recv[4*q+1] += v.y * w;
                recv[4*q+2] += v.z * w;
                recv[4*q+3] += v.w * w;
            }
        }
    }
    // cc injection (neurons 0..3)
    if (c < kALPHA) {
        const float* src = cc + (size_t)b * (kNC * kD) + nc * kD;
        #pragma unroll
        for (int d = 0; d < 32; ++d) recv[d] += src[d];
    }

    // ---- state MLP: s_in = [h(32), recv(32), pnew(32), decay] ----
    // W1 rows via wave-uniform s_load (scalar pipe); W2^T rows via 8 LDS
    // broadcasts. Biases wave-uniform -> s_load.
    float dh[32];
    #pragma unroll
    for (int o = 0; o < 32; ++o) dh[o] = sb2[o];
    #pragma unroll 2
    for (int hh = 0; hh < kHS; ++hh) {
        const float* w = sw1 + hh * (3 * kD + 1);   // uniform -> s_load
        float acc = sb1[hh] + decay * w[96];
        #pragma unroll
        for (int i = 0; i < 32; ++i) acc += hreg[i] * w[i];
        #pragma unroll
        for (int i = 0; i < 32; ++i) acc += recv[i] * w[32 + i];
        #pragma unroll
        for (int i = 0; i < 32; ++i) acc += pnew[i] * w[64 + i];
        const float s = tanhf(acc);
        const float4* w2r = (const float4*)(w2ts + hh * kW2TS);
        #pragma unroll
        for (int q = 0; q < 8; ++q) {
            float4 wv = w2r[q];
            dh[4*q]   += s * wv.x;
            dh[4*q+1] += s * wv.y;
            dh[4*q+2] += s * wv.z;
            dh[4*q+3] += s * wv.w;
        }
    }
    float hnew[32];
    #pragma unroll
    for (int d = 0; d < 32; ++d) hnew[d] = decay * hreg[d] + (1.f - decay) * tanhf(dh[d]);

    // write h_new
    {
        float4* dst = (float4*)(out + kO1 + nbase * kD);
        #pragma unroll
        for (int q = 0; q < 8; ++q)
            dst[q] = make_float4(hnew[4*q], hnew[4*q+1], hnew[4*q+2], hnew[4*q+3]);
    }

    // ---- msg MLP: m_in = [h_new(32), recv(32), nid(32)] ----
    float nidr[32];
    {
        const float4* src = (const float4*)(nid + ((size_t)nc * kC + c) * kD);
        #pragma unroll
        for (int q = 0; q < 8; ++q) {
            float4 v = src[q];
            nidr[4*q] = v.x; nidr[4*q+1] = v.y; nidr[4*q+2] = v.z; nidr[4*q+3] = v.w;
        }
    }
    float mm[32];
    #pragma unroll
    for (int o = 0; o < 32; ++o) mm[o] = mb2g[o];
    #pragma unroll 2
    for (int hh = 0; hh < kHM; ++hh) {
        const float* w = mw1g + hh * (3 * kD);      // uniform -> s_load
        float acc = mb1g[hh];
        #pragma unroll
        for (int i = 0; i < 32; ++i) acc += hnew[i] * w[i];
        #pragma unroll
        for (int i = 0; i < 32; ++i) acc += recv[i] * w[32 + i];
        #pragma unroll
        for (int i = 0; i < 32; ++i) acc += nidr[i] * w[64 + i];
        const float s = tanhf(acc);
        const float4* w2r = (const float4*)(mw2ts + hh * kW2TS);
        #pragma unroll
        for (int q = 0; q < 8; ++q) {
            float4 wv = w2r[q];
            mm[4*q]   += s * wv.x;
            mm[4*q+1] += s * wv.y;
            mm[4*q+2] += s * wv.z;
            mm[4*q+3] += s * wv.w;
        }
    }
    float msgr[32];
    #pragma unroll
    for (int d = 0; d < 32; ++d) msgr[d] = tanhf(mm[d]);

    __syncthreads();   // everyone done reading prev_messages from slab
    {
        float4* row = (float4*)(slab + c * kSLAB);
        #pragma unroll
        for (int q = 0; q < 8; ++q)
            row[q] = make_float4(msgr[4*q], msgr[4*q+1], msgr[4*q+2], msgr[4*q+3]);
    }
    __syncthreads();

    // ---- hebbian update: corr[k] = (msg . msg[conn[k]]) / D ----
    {
        const float* hb = hebin + nbase * kK;
        float* dst = out + kO3 + nbase * kK;
        #pragma unroll 1
        for (int k = 0; k < 16; ++k) {
            const float4* row = (const float4*)(slab + jreg[k] * kSLAB);
            float dot = 0.f;
            #pragma unroll
            for (int q = 0; q < 8; ++q) {
                float4 v = row[q];
                dot += msgr[4*q] * v.x + msgr[4*q+1] * v.y
                     + msgr[4*q+2] * v.z + msgr[4*q+3] * v.w;
            }
            dst[k] = 0.9f * hb[k] + 0.1f * (dot * (1.0f / 32.0f));
        }
    }
    // msg output, coalesced via LDS
    {
        float4* dst = (float4*)(out + kO2 + cellrow * kD);
        for (int i = c; i < (kC * kD) / 4; i += kC)
            dst[i] = *(const float4*)&slab[(i >> 3) * kSLAB + ((i & 7) << 2)];
    }
    // readout: mean of last ALPHA=4 neurons' msg
    if (c < kD) {
        float s = 0.25f * (slab[(kC-4)*kSLAB + c] + slab[(kC-3)*kSLAB + c] +
                           slab[(kC-2)*kSLAB + c] + slab[(kC-1)*kSLAB + c]);
        out[(size_t)b * (kNC * kD) + nc * kD + c] = s;
    }
}

extern "C" void kernel_launch(void* const* d_in, const int* in_sizes, int n_in,
                              void* d_out, int out_size, void* d_ws, size_t ws_size,
                              hipStream_t stream)
{
    const float* cc    = (const float*)d_in[0];
    const float* h     = (const float*)d_in[1];
    const float* pmsg  = (const float*)d_in[2];
    const float* dlog  = (const float*)d_in[3];
    const float* prim  = (const float*)d_in[4];
    const float* heb   = (const float*)d_in[5];
    const float* sw1   = (const float*)d_in[6];
    const float* sb1   = (const float*)d_in[7];
    const float* sw2   = (const float*)d_in[8];
    const float* sb2   = (const float*)d_in[9];
    const float* mw1   = (const float*)d_in[10];
    const float* mb1   = (const float*)d_in[11];
    const float* mw2   = (const float*)d_in[12];
    const float* mb2   = (const float*)d_in[13];
    const float* modw1 = (const float*)d_in[14];
    const float* modb1 = (const float*)d_in[15];
    const float* modw2 = (const float*)d_in[16];
    const float* modb2 = (const float*)d_in[17];
    const float* nid   = (const float*)d_in[18];
    const int*   conn  = (const int*)d_in[19];
    const int*   bconn = (const int*)d_in[20];
    float* out = (float*)d_out;
    float* modout = (float*)d_ws;

    // padded modout rows (60 words, prim-delta 16B-aligned at word 28) if the
    // workspace allows; otherwise the original tight 57-word layout.
    int mos = 57, poff = 25;
    if (ws_size >= (size_t)kBS * kN * 60 * sizeof(float)) { mos = 60; poff = 28; }

    mod_mlp_kernel<<<kN, 256, 0, stream>>>(heb, h, dlog, prim, nid,
                                           modw1, modb1, modw2, modb2,
                                           modout, mos, poff);
    cell_kernel<<<dim3(kNC, kBS), kC, 0, stream>>>(cc, h, pmsg, prim, heb, nid,
                                                   sw1, sb1, sw2, sb2,
                                                   mw1, mb1, mw2, mb2,
                                                   conn, bconn, modout, out,
                                                   mos, poff);
}

// Round 5
// 712.915 us; speedup vs baseline: 1.3386x; 1.0228x over previous
//
#include <hip/hip_runtime.h>
#include <cstdint>
#include <cstddef>

constexpr int kBS = 8;
constexpr int kNC = 64;
constexpr int kC = 256;
constexpr int kD = 32;
constexpr int kK = 16;
constexpr int kKB = 8;
constexpr int kALPHA = 4;
constexpr int kB = 16;
constexpr int kHS = 64;
constexpr int kHM = 64;
constexpr int kHMOD = 32;
constexpr int kN = kNC * kC;               // 16384
constexpr int kMODIN = kK + 3 * kD + 1;    // 113
constexpr int kMODOUT = kK + kKB + 1 + kD; // 57
constexpr int kXS = 116;                   // mod x/W1 LDS row stride (464B)
constexpr int kSLAB = 36;                  // slab row stride (144B)
constexpr int kW2TS = 36;                  // cell transposed-W2 LDS row stride

constexpr size_t kO1 = (size_t)kBS * kNC * kD;        // readout
constexpr size_t kO2 = kO1 + (size_t)kBS * kN * kD;   // + h_new
constexpr size_t kO3 = kO2 + (size_t)kBS * kN * kD;   // + msg

__device__ __forceinline__ float sigmoidf_(float x) {
    return 1.0f / (1.0f + __expf(-x));
}

// ---------------- Kernel A: per-neuron modulation MLP --------------------
// ONE WAVE PER NEURON (4 waves/block, wave-private LDS, no barriers).
// Lane = (b:8, half:2, hq:4). x chunk (56 f) held in REGISTERS (read once,
// aligned b128 from LDS). W1 broadcast from LDS with 8 unique addrs/read
// (hh = s*4+hq -> distinct banks) => W1 crosses the LDS pipe ONCE per
// neuron (round 2-4 read it 8x and x 32x -> LDS-issue wall ~150us).
// Layer 2: W2 columns loaded coalesced from GLOBAL into registers
// (lane = output col), hid broadcast from LDS.
__global__ __launch_bounds__(256) void mod_mlp_kernel(
    const float* __restrict__ heb, const float* __restrict__ h,
    const float* __restrict__ dlog, const float* __restrict__ prim,
    const float* __restrict__ nid,
    const float* __restrict__ mw1, const float* __restrict__ mb1,
    const float* __restrict__ mw2, const float* __restrict__ mb2,
    float* __restrict__ modout, int mos, int poff)
{
    const int wv = threadIdx.x >> 6;
    const int lane = threadIdx.x & 63;
    const int n = (blockIdx.x << 2) | wv;

    __shared__ __align__(16) float xs[4][kBS * kXS];      // 4 x 3712 B
    __shared__ __align__(16) float w1sh[4][kHMOD * kXS];  // 4 x 14848 B
    __shared__ __align__(16) float hs[4][kBS * kHMOD];    // 4 x 1024 B
    float* xw  = xs[wv];
    float* w1s = w1sh[wv];
    float* hid = hs[wv];

    // ---- stage W1 into padded LDS (coalesced float4 global reads) ----
    {
        const float4* w1g4 = (const float4*)(mw1 + (size_t)n * (kHMOD * kMODIN));
        for (int t = lane; t < (kHMOD * kMODIN) / 4; t += 64) {
            float4 v = w1g4[t];
            int f = t << 2;
            #pragma unroll
            for (int e = 0; e < 4; ++e) {
                int fe = f + e;
                int r = fe / kMODIN;
                int c = fe - r * kMODIN;
                float val = (e == 0) ? v.x : (e == 1) ? v.y : (e == 2) ? v.z : v.w;
                w1s[r * kXS + c] = val;
            }
        }
    }
    // ---- stage x: [heb 0..15][h 16..47][dlog 48][prim 49..80][nid 81..112] ----
    {
        {   // heb: 128 elems, 2 rounds
            int t = lane;          int b0 = t >> 4,  i0 = t & 15;
            xw[b0 * kXS + i0] = heb[((size_t)b0 * kN + n) * kK + i0];
            t += 64;               int b1 = t >> 4,  i1 = t & 15;
            xw[b1 * kXS + i1] = heb[((size_t)b1 * kN + n) * kK + i1];
        }
        #pragma unroll
        for (int r = 0; r < 4; ++r) {   // h / prim / nid: 256 each
            int t = lane + 64 * r;
            int b = t >> 5, d = t & 31;
            xw[b * kXS + 16 + d] = h[((size_t)b * kN + n) * kD + d];
            xw[b * kXS + 49 + d] = prim[((size_t)b * kN + n) * kD + d];
            xw[b * kXS + 81 + d] = nid[(size_t)n * kD + d];
        }
        if (lane < kBS)
            xw[lane * kXS + 48] = dlog[(size_t)lane * kN + n];
    }
    // same-wave LDS RAW: in-order LDS pipe per wave + compiler lgkmcnt.

    const int b    = lane >> 3;        // batch
    const int half = (lane >> 2) & 1;  // x half (0: cols 0..55, 1: 56..111)
    const int hq   = lane & 3;

    // ---- x chunk into registers (aligned b128: b*464B + half*224B) ----
    float4 xr[14];
    {
        const float* xbase = xw + b * kXS + half * 56;
        #pragma unroll
        for (int q = 0; q < 14; ++q)
            xr[q] = *(const float4*)(xbase + 4 * q);
    }
    const float x112 = (half == 1) ? xw[b * kXS + 112] : 0.0f;

    // ---- layer 1: 8 hidden per lane (hh = s*4 + hq), reduce across halves ----
    #pragma unroll
    for (int s = 0; s < 8; ++s) {
        const int hh = (s << 2) + hq;
        const float* wrow = w1s + hh * kXS + half * 56;
        float p0 = 0.f, p1 = 0.f, p2 = 0.f, p3 = 0.f;
        #pragma unroll
        for (int q = 0; q < 14; ++q) {
            float4 wv4 = *(const float4*)(wrow + 4 * q);
            p0 += wv4.x * xr[q].x; p1 += wv4.y * xr[q].y;
            p2 += wv4.z * xr[q].z; p3 += wv4.w * xr[q].w;
        }
        float acc = ((p0 + p1) + (p2 + p3)) + w1s[hh * kXS + 112] * x112;
        acc += __shfl_xor(acc, 4, 64);   // combine the two halves
        const float hv = tanhf(acc + mb1[(size_t)n * kHMOD + hh]);
        if (half == 0) hid[b * kHMOD + hh] = hv;
    }

    // ---- layer 2: lane = output column o; W2 col loaded coalesced ----
    const int o = (lane < kMODOUT) ? lane : (kMODOUT - 1);
    float w2c[kHMOD];
    {
        const float* w2g = mw2 + (size_t)n * (kHMOD * kMODOUT) + o;
        #pragma unroll
        for (int hx = 0; hx < kHMOD; ++hx)
            w2c[hx] = w2g[hx * kMODOUT];
    }
    const float bo = mb2[(size_t)n * kMODOUT + o];
    const int oo = (o < 25) ? o : (o + (poff - 25));
    #pragma unroll
    for (int b2 = 0; b2 < kBS; ++b2) {
        const float4* h4 = (const float4*)(hid + b2 * kHMOD); // broadcast reads
        float acc = bo;
        #pragma unroll
        for (int j = 0; j < 8; ++j) {
            float4 hv = h4[j];
            acc += hv.x * w2c[4*j] + hv.y * w2c[4*j+1]
                 + hv.z * w2c[4*j+2] + hv.w * w2c[4*j+3];
        }
        if (lane < kMODOUT)
            modout[((size_t)b2 * kN + n) * mos + oo] = acc;
    }
}

// ---------------- Kernel B: per-cell message passing + state/msg MLPs -----
// One block per (b,nc); one thread per neuron c. W1 rows via wave-uniform
// s_load; W2^T in LDS (8 broadcasts/hh). THIS ROUND: dot products split into
// 4 independent partial accumulators (round-4 had a single 97-deep dependent
// FMA chain, ~388 cyc latency vs ~194 cyc issue -> unhidable at 2 waves/SIMD).
__global__ __launch_bounds__(256) void cell_kernel(
    const float* __restrict__ cc, const float* __restrict__ hin,
    const float* __restrict__ pmsg, const float* __restrict__ prim,
    const float* __restrict__ hebin, const float* __restrict__ nid,
    const float* __restrict__ sw1, const float* __restrict__ sb1,
    const float* __restrict__ sw2, const float* __restrict__ sb2,
    const float* __restrict__ mw1g, const float* __restrict__ mb1g,
    const float* __restrict__ mw2g, const float* __restrict__ mb2g,
    const int* __restrict__ conn, const int* __restrict__ bconn,
    const float* __restrict__ modout, float* __restrict__ out,
    int mos, int poff)
{
    const int nc = blockIdx.x;
    const int b  = blockIdx.y;
    const int c  = threadIdx.x;

    __shared__ __align__(16) float slab[kC * kSLAB];      // 36864 B
    __shared__ __align__(16) float w2ts[kHS * kW2TS];     //  9216 B (state W2^T)
    __shared__ __align__(16) float mw2ts[kHM * kW2TS];    //  9216 B (msg W2^T)
    // total ~55 KB -> both resident blocks/CU fit

    const size_t cellrow = ((size_t)b * kNC + nc) * kC;
    const size_t nbase   = cellrow + c;

    // ---- stage transposed W2 matrices ----
    for (int idx = c; idx < kHS * kD; idx += kC) {   // sw2 is [o=32][hh=64]
        int o2 = idx >> 6, h2 = idx & 63;
        w2ts[h2 * kW2TS + o2] = sw2[idx];
    }
    for (int idx = c; idx < kHM * kD; idx += kC) {
        int o2 = idx >> 6, h2 = idx & 63;
        mw2ts[h2 * kW2TS + o2] = mw2g[idx];
    }

    // ---- stage this cell's prev_messages (coalesced, float4) ----
    {
        const float4* s4 = (const float4*)(pmsg + cellrow * kD);
        for (int i = c; i < (kC * kD) / 4; i += kC) {
            float4 v = s4[i];
            *(float4*)&slab[(i >> 3) * kSLAB + ((i & 7) << 2)] = v;
        }
    }

    // ---- per-thread loads (overlap with staging) ----
    float hreg[32];
    {
        const float4* src = (const float4*)(hin + nbase * kD);
        #pragma unroll
        for (int q = 0; q < 8; ++q) {
            float4 v = src[q];
            hreg[4*q] = v.x; hreg[4*q+1] = v.y; hreg[4*q+2] = v.z; hreg[4*q+3] = v.w;
        }
    }
    const float* mo = modout + nbase * mos;
    float wcon[16];
    #pragma unroll
    for (int k = 0; k < 16; ++k) wcon[k] = sigmoidf_(mo[k]);
    int jreg[16];
    {
        const int4* cr = (const int4*)(conn + ((size_t)nc * kC + c) * kK);
        #pragma unroll
        for (int q = 0; q < 4; ++q) {
            int4 v = cr[q];
            jreg[4*q] = v.x; jreg[4*q+1] = v.y; jreg[4*q+2] = v.z; jreg[4*q+3] = v.w;
        }
    }
    const float decay = sigmoidf_(mo[kK + kKB]);
    float pnew[32];
    {
        const float4* p4 = (const float4*)(prim + nbase * kD);
        const int pbase = poff;
        #pragma unroll
        for (int q = 0; q < 8; ++q) {
            float4 v = p4[q];
            pnew[4*q]   = v.x + mo[pbase + 4*q];
            pnew[4*q+1] = v.y + mo[pbase + 4*q + 1];
            pnew[4*q+2] = v.z + mo[pbase + 4*q + 2];
            pnew[4*q+3] = v.w + mo[pbase + 4*q + 3];
        }
    }
    __syncthreads();

    // ---- received = sum_k sigmoid(w_conn[k]) * prev_msg[conn[k]] ----
    float recv[32];
    #pragma unroll
    for (int d = 0; d < 32; ++d) recv[d] = 0.f;
    #pragma unroll 1
    for (int k = 0; k < 16; ++k) {
        const float4* row = (const float4*)(slab + jreg[k] * kSLAB);
        const float w = wcon[k];
        #pragma unroll
        for (int q = 0; q < 8; ++q) {
            float4 v = row[q];
            recv[4*q]   += v.x * w;
            recv[4*q+1] += v.y * w;
            recv[4*q+2] += v.z * w;
            recv[4*q+3] += v.w * w;
        }
    }
    // border contributions (neurons 4..19)
    if (c >= kALPHA && c < kALPHA + kB) {
        const int j = c - kALPHA;
        const int* br = bconn + ((size_t)nc * kB + j) * kKB;
        #pragma unroll 1
        for (int kb = 0; kb < kKB; ++kb) {
            int g = br[kb];
            int nc2 = g >> 4;
            int c2 = kALPHA + (g & 15);
            const float4* src = (const float4*)(pmsg + (((size_t)b * kNC + nc2) * kC + c2) * kD);
            float w = sigmoidf_(mo[kK + kb]);
            #pragma unroll
            for (int q = 0; q < 8; ++q) {
                float4 v = src[q];
                recv[4*q]   += v.x * w;
                recv[4*q+1] += v.y * w;
                recv[4*q+2] += v.z * w;
                recv[4*q+3] += v.w * w;
            }
        }
    }
    // cc injection (neurons 0..3)
    if (c < kALPHA) {
        const float* src = cc + (size_t)b * (kNC * kD) + nc * kD;
        #pragma unroll
        for (int d = 0; d < 32; ++d) recv[d] += src[d];
    }

    // ---- state MLP: s_in = [h(32), recv(32), pnew(32), decay] ----
    float dh[32];
    #pragma unroll
    for (int o = 0; o < 32; ++o) dh[o] = sb2[o];
    #pragma unroll 2
    for (int hh = 0; hh < kHS; ++hh) {
        const float* w = sw1 + hh * (3 * kD + 1);   // uniform -> s_load
        float p0 = 0.f, p1 = 0.f, p2 = 0.f, p3 = 0.f;
        #pragma unroll
        for (int q = 0; q < 8; ++q) {
            p0 += hreg[4*q+0] * w[4*q+0];
            p1 += hreg[4*q+1] * w[4*q+1];
            p2 += hreg[4*q+2] * w[4*q+2];
            p3 += hreg[4*q+3] * w[4*q+3];
        }
        #pragma unroll
        for (int q = 0; q < 8; ++q) {
            p0 += recv[4*q+0] * w[32 + 4*q+0];
            p1 += recv[4*q+1] * w[32 + 4*q+1];
            p2 += recv[4*q+2] * w[32 + 4*q+2];
            p3 += recv[4*q+3] * w[32 + 4*q+3];
        }
        #pragma unroll
        for (int q = 0; q < 8; ++q) {
            p0 += pnew[4*q+0] * w[64 + 4*q+0];
            p1 += pnew[4*q+1] * w[64 + 4*q+1];
            p2 += pnew[4*q+2] * w[64 + 4*q+2];
            p3 += pnew[4*q+3] * w[64 + 4*q+3];
        }
        float acc = sb1[hh] + decay * w[96] + ((p0 + p1) + (p2 + p3));
        const float s = tanhf(acc);
        const float4* w2r = (const float4*)(w2ts + hh * kW2TS);
        #pragma unroll
        for (int q = 0; q < 8; ++q) {
            float4 wv = w2r[q];
            dh[4*q]   += s * wv.x;
            dh[4*q+1] += s * wv.y;
            dh[4*q+2] += s * wv.z;
            dh[4*q+3] += s * wv.w;
        }
    }
    float hnew[32];
    #pragma unroll
    for (int d = 0; d < 32; ++d) hnew[d] = decay * hreg[d] + (1.f - decay) * tanhf(dh[d]);

    // write h_new
    {
        float4* dst = (float4*)(out + kO1 + nbase * kD);
        #pragma unroll
        for (int q = 0; q < 8; ++q)
            dst[q] = make_float4(hnew[4*q], hnew[4*q+1], hnew[4*q+2], hnew[4*q+3]);
    }

    // ---- msg MLP: m_in = [h_new(32), recv(32), nid(32)] ----
    float nidr[32];
    {
        const float4* src = (const float4*)(nid + ((size_t)nc * kC + c) * kD);
        #pragma unroll
        for (int q = 0; q < 8; ++q) {
            float4 v = src[q];
            nidr[4*q] = v.x; nidr[4*q+1] = v.y; nidr[4*q+2] = v.z; nidr[4*q+3] = v.w;
        }
    }
    float mm[32];
    #pragma unroll
    for (int o = 0; o < 32; ++o) mm[o] = mb2g[o];
    #pragma unroll 2
    for (int hh = 0; hh < kHM; ++hh) {
        const float* w = mw1g + hh * (3 * kD);      // uniform -> s_load
        float p0 = 0.f, p1 = 0.f, p2 = 0.f, p3 = 0.f;
        #pragma unroll
        for (int q = 0; q < 8; ++q) {
            p0 += hnew[4*q+0] * w[4*q+0];
            p1 += hnew[4*q+1] * w[4*q+1];
            p2 += hnew[4*q+2] * w[4*q+2];
            p3 += hnew[4*q+3] * w[4*q+3];
        }
        #pragma unroll
        for (int q = 0; q < 8; ++q) {
            p0 += recv[4*q+0] * w[32 + 4*q+0];
            p1 += recv[4*q+1] * w[32 + 4*q+1];
            p2 += recv[4*q+2] * w[32 + 4*q+2];
            p3 += recv[4*q+3] * w[32 + 4*q+3];
        }
        #pragma unroll
        for (int q = 0; q < 8; ++q) {
            p0 += nidr[4*q+0] * w[64 + 4*q+0];
            p1 += nidr[4*q+1] * w[64 + 4*q+1];
            p2 += nidr[4*q+2] * w[64 + 4*q+2];
            p3 += nidr[4*q+3] * w[64 + 4*q+3];
        }
        const float s = tanhf(mb1g[hh] + ((p0 + p1) + (p2 + p3)));
        const float4* w2r = (const float4*)(mw2ts + hh * kW2TS);
        #pragma unroll
        for (int q = 0; q < 8; ++q) {
            float4 wv = w2r[q];
            mm[4*q]   += s * wv.x;
            mm[4*q+1] += s * wv.y;
            mm[4*q+2] += s * wv.z;
            mm[4*q+3] += s * wv.w;
        }
    }
    float msgr[32];
    #pragma unroll
    for (int d = 0; d < 32; ++d) msgr[d] = tanhf(mm[d]);

    __syncthreads();   // everyone done reading prev_messages from slab
    {
        float4* row = (float4*)(slab + c * kSLAB);
        #pragma unroll
        for (int q = 0; q < 8; ++q)
            row[q] = make_float4(msgr[4*q], msgr[4*q+1], msgr[4*q+2], msgr[4*q+3]);
    }
    __syncthreads();

    // ---- hebbian update: corr[k] = (msg . msg[conn[k]]) / D ----
    {
        const float* hb = hebin + nbase * kK;
        float* dst = out + kO3 + nbase * kK;
        #pragma unroll 1
        for (int k = 0; k < 16; ++k) {
            const float4* row = (const float4*)(slab + jreg[k] * kSLAB);
            float dot = 0.f;
            #pragma unroll
            for (int q = 0; q < 8; ++q) {
                float4 v = row[q];
                dot += msgr[4*q] * v.x + msgr[4*q+1] * v.y
                     + msgr[4*q+2] * v.z + msgr[4*q+3] * v.w;
            }
            dst[k] = 0.9f * hb[k] + 0.1f * (dot * (1.0f / 32.0f));
        }
    }
    // msg output, coalesced via LDS
    {
        float4* dst = (float4*)(out + kO2 + cellrow * kD);
        for (int i = c; i < (kC * kD) / 4; i += kC)
            dst[i] = *(const float4*)&slab[(i >> 3) * kSLAB + ((i & 7) << 2)];
    }
    // readout: mean of last ALPHA=4 neurons' msg
    if (c < kD) {
        float s = 0.25f * (slab[(kC-4)*kSLAB + c] + slab[(kC-3)*kSLAB + c] +
                           slab[(kC-2)*kSLAB + c] + slab[(kC-1)*kSLAB + c]);
        out[(size_t)b * (kNC * kD) + nc * kD + c] = s;
    }
}

extern "C" void kernel_launch(void* const* d_in, const int* in_sizes, int n_in,
                              void* d_out, int out_size, void* d_ws, size_t ws_size,
                              hipStream_t stream)
{
    const float* cc    = (const float*)d_in[0];
    const float* h     = (const float*)d_in[1];
    const float* pmsg  = (const float*)d_in[2];
    const float* dlog  = (const float*)d_in[3];
    const float* prim  = (const float*)d_in[4];
    const float* heb   = (const float*)d_in[5];
    const float* sw1   = (const float*)d_in[6];
    const float* sb1   = (const float*)d_in[7];
    const float* sw2   = (const float*)d_in[8];
    const float* sb2   = (const float*)d_in[9];
    const float* mw1   = (const float*)d_in[10];
    const float* mb1   = (const float*)d_in[11];
    const float* mw2   = (const float*)d_in[12];
    const float* mb2   = (const float*)d_in[13];
    const float* modw1 = (const float*)d_in[14];
    const float* modb1 = (const float*)d_in[15];
    const float* modw2 = (const float*)d_in[16];
    const float* modb2 = (const float*)d_in[17];
    const float* nid   = (const float*)d_in[18];
    const int*   conn  = (const int*)d_in[19];
    const int*   bconn = (const int*)d_in[20];
    float* out = (float*)d_out;
    float* modout = (float*)d_ws;

    // padded modout rows (60 words, prim-delta 16B-aligned at word 28) if the
    // workspace allows; otherwise the original tight 57-word layout.
    int mos = 57, poff = 25;
    if (ws_size >= (size_t)kBS * kN * 60 * sizeof(float)) { mos = 60; poff = 28; }

    mod_mlp_kernel<<<kN / 4, 256, 0, stream>>>(heb, h, dlog, prim, nid,
                                               modw1, modb1, modw2, modb2,
                                               modout, mos, poff);
    cell_kernel<<<dim3(kNC, kBS), kC, 0, stream>>>(cc, h, pmsg, prim, heb, nid,
                                                   sw1, sb1, sw2, sb2,
                                                   mw1, mb1, mw2, mb2,
                                                   conn, bconn, modout, out,
                                                   mos, poff);
}